// Round 1
// baseline (4763.535 us; speedup 1.0000x reference)
//
#include <hip/hip_runtime.h>
#include <cstdint>

typedef _Float16 half8 __attribute__((ext_vector_type(8)));
typedef _Float16 half4v __attribute__((ext_vector_type(4)));
typedef float floatx4 __attribute__((ext_vector_type(4)));
typedef unsigned long long u64;

__device__ __forceinline__ float sig_(float x) { return 1.f / (1.f + __expf(-x)); }
__device__ __forceinline__ float tanh_(float x) {
  x = fminf(15.f, fmaxf(-15.f, x));
  float e = __expf(2.f * x);
  return (e - 1.f) / (e + 1.f);
}

// ---------------- prep kernels ----------------
__global__ void cvt_x_kernel(const float* __restrict__ x, _Float16* __restrict__ xh, int n) {
  int i = (blockIdx.x * 256 + threadIdx.x) * 4;
  if (i < n) {
    const float4 v = *(const float4*)(x + i);
    half4v o = {(_Float16)v.x, (_Float16)v.y, (_Float16)v.z, (_Float16)v.w};
    *(half4v*)(xh + i) = o;
  }
}

// Permuted weights: row n of W*perm = w_{g}[u][:], u=n>>2, g=n&3.
__global__ void build_w_kernel(const float* w0, const float* w1, const float* w2, const float* w3,
                               const float* w4, const float* w5, const float* w6, const float* w7,
                               const float* b0, const float* b1, const float* b2, const float* b3,
                               _Float16* __restrict__ Wip, _Float16* __restrict__ Whp,
                               float* __restrict__ biasp) {
  int n = blockIdx.x;
  if (n < 8192) {
    const float* srcs[8] = {w0, w1, w2, w3, w4, w5, w6, w7};
    int which = n >> 12;
    int row = n & 4095;
    int u = row >> 2, g = row & 3;
    const float* s = srcs[which * 4 + g] + (size_t)u * 1024;
    _Float16* dst = (which ? Whp : Wip) + (size_t)row * 1024;
    int t = threadIdx.x * 4;
    float4 v = *(const float4*)(s + t);
    half4v o = {(_Float16)v.x, (_Float16)v.y, (_Float16)v.z, (_Float16)v.w};
    *(half4v*)(dst + t) = o;
  } else {
    const float* bs[4] = {b0, b1, b2, b3};
    for (int idx = threadIdx.x; idx < 4096; idx += 256)
      biasp[idx] = bs[idx & 3][idx >> 2];
  }
}

// h buffers: fp16 pairs packed in u32, row-major [batch][unit]
__global__ void init_h_kernel(const float* __restrict__ hx, unsigned int* __restrict__ hbuf) {
  int i = blockIdx.x * 256 + threadIdx.x;
  if (i < 32768) {
    unsigned short lo = __builtin_bit_cast(unsigned short, (_Float16)hx[2 * i]);
    unsigned short hi = __builtin_bit_cast(unsigned short, (_Float16)hx[2 * i + 1]);
    hbuf[i] = (unsigned int)lo | ((unsigned int)hi << 16);
  }
}

__global__ void zero_flags_kernel(unsigned int* __restrict__ flags) {
  int i = blockIdx.x * 256 + threadIdx.x;
  if (i < 8192) flags[i] = 0u;
}

// ---------------- precompute GEMM ----------------
// G3 layout (fp16): [p(256)][t(512)][i(4)][kg(4)][ml(16)][r(4)]
__global__ __launch_bounds__(256) void gemm_g_kernel(const _Float16* __restrict__ Xh,
                                                     const _Float16* __restrict__ Wp,
                                                     const float* __restrict__ biasp,
                                                     _Float16* __restrict__ G3) {
  __shared__ _Float16 Al[4][128][8];
  __shared__ _Float16 Bl[4][128][8];
  const int tid = threadIdx.x;
  const int w = tid >> 6, l = tid & 63;
  const int wm = (w >> 1) * 64, wn = (w & 1) * 64;
  const int ml = l & 15, kg = l >> 4;
  const int bm = blockIdx.x, bn = blockIdx.y;
  const int r0 = tid & 127, kc0 = tid >> 7;
  const int kc1 = kc0 + 2;
  const size_t arow0 = (size_t)(bm * 128 + r0) * 1024;
  const size_t brow0 = (size_t)(bn * 128 + r0) * 1024;
  floatx4 acc[4][4] = {};
  for (int kt = 0; kt < 1024; kt += 32) {
    __syncthreads();
    __builtin_amdgcn_global_load_lds(
        (const __attribute__((address_space(1))) unsigned int*)(Xh + arow0 + kt + kc0 * 8),
        (__attribute__((address_space(3))) unsigned int*)&Al[kc0][r0][0], 16, 0, 0);
    __builtin_amdgcn_global_load_lds(
        (const __attribute__((address_space(1))) unsigned int*)(Xh + arow0 + kt + kc1 * 8),
        (__attribute__((address_space(3))) unsigned int*)&Al[kc1][r0][0], 16, 0, 0);
    __builtin_amdgcn_global_load_lds(
        (const __attribute__((address_space(1))) unsigned int*)(Wp + brow0 + kt + kc0 * 8),
        (__attribute__((address_space(3))) unsigned int*)&Bl[kc0][r0][0], 16, 0, 0);
    __builtin_amdgcn_global_load_lds(
        (const __attribute__((address_space(1))) unsigned int*)(Wp + brow0 + kt + kc1 * 8),
        (__attribute__((address_space(3))) unsigned int*)&Bl[kc1][r0][0], 16, 0, 0);
    __syncthreads();
    half8 af[4], bf[4];
#pragma unroll
    for (int i = 0; i < 4; ++i) af[i] = *(const half8*)&Al[kg][wm + i * 16 + ml][0];
#pragma unroll
    for (int j = 0; j < 4; ++j) bf[j] = *(const half8*)&Bl[kg][wn + j * 16 + ml][0];
#pragma unroll
    for (int i = 0; i < 4; ++i)
#pragma unroll
      for (int j = 0; j < 4; ++j)
        acc[i][j] = __builtin_amdgcn_mfma_f32_16x16x32_f16(af[i], bf[j], acc[i][j], 0, 0, 0);
  }
  const int t = (bm * 128 + wm) >> 6;
#pragma unroll
  for (int j = 0; j < 4; ++j) {
    const int col = bn * 128 + wn + j * 16 + ml;
    const float bj = biasp[col];
    const int p = col >> 4;
#pragma unroll
    for (int i = 0; i < 4; ++i) {
      half4v pk = {(_Float16)(acc[i][j][0] + bj), (_Float16)(acc[i][j][1] + bj),
                   (_Float16)(acc[i][j][2] + bj), (_Float16)(acc[i][j][3] + bj)};
      *(half4v*)&G3[((size_t)p * 512 + t) * 1024 + i * 256 + kg * 64 + ml * 4] = pk;
    }
  }
}

// ---------------- persistent recurrent kernel ----------------
// 128 blocks x 512 threads (8 waves, 2/SIMD). Block p owns units [8p,8p+8) = perm
// cols [32p,32p+32). Wave (bg=w&3, cg=w>>2): batches [16bg,+16) x cols [32p+16cg,+16).
// Full h (128 KB) staged ONCE per block into shared XOR-swizzled LDS slices (halves
// global broadcast traffic vs 256-block version: 16 MB/step instead of 32 MB/step).
// Barrier: contiguous flags, wave-0-only coalesced poll, LDS token release.
__global__ __launch_bounds__(512, 2) void lstm_rec_kernel(
    const _Float16* __restrict__ G3, const _Float16* __restrict__ Whp,
    unsigned int* __restrict__ hbuf, const float* __restrict__ cx,
    float* __restrict__ out, unsigned int* __restrict__ flags) {
  const int p = blockIdx.x, tid = threadIdx.x;
  const int w = tid >> 6, l = tid & 63;
  const int bg = w & 3, cg = w >> 2;
  const int ml = l & 15, kg = l >> 4;
  // LDS: 8 slices x 16 KB h-stage (chunk c, batch-group bgr at (c*4+bgr)*16384),
  // then 8 x 1280 B gate scratch at 131072, token at 141312.
  __shared__ __align__(16) char lds[141328];

  // persistent Wh B-fragments: lane (ml,kg) holds Whp[32p+16cg+ml][s*32+kg*8 .. +8]
  half8 wfr[32];
  const size_t wrow = (size_t)(32 * p + 16 * cg + ml) * 1024;
#pragma unroll
  for (int s = 0; s < 32; ++s)
    wfr[s] = *(const half8*)&Whp[wrow + s * 32 + kg * 8];

  const int bl = l >> 2, u = l & 3;
  const int batch = 16 * bg + bl;
  const int U = 8 * p + 4 * cg + u;
  float c = cx[batch * 1024 + U];

  const int tq = tid >> 7;   // 0..3: which of 4 rows per i-group this thread loads
  const int j0 = tid & 127;  // u64 index within row-chunk
  unsigned* tok = (unsigned*)(lds + 141312);
  if (tid == 0) *tok = 0u;
  float* glw = (float*)(lds + 131072) + w * 320;  // 16x20 f32 per wave
  __syncthreads();

  for (int t = 0; t < 512; ++t) {
    const u64* hq = (const u64*)hbuf + (size_t)(t & 1) * 16384;
    u64* hnq = (u64*)hbuf + (size_t)((t & 1) ^ 1) * 16384;

    // ---- issue all global traffic up front (coalesced: 128 threads per row) ----
    u64 c1[16], c2[16];
#pragma unroll
    for (int i = 0; i < 16; ++i) {
      const int rg = i * 4 + tq;
      c1[i] = __hip_atomic_load(&hq[(size_t)rg * 256 + j0], __ATOMIC_RELAXED,
                                __HIP_MEMORY_SCOPE_AGENT);
    }
    const u64 ginb = *(const u64*)&G3[((size_t)(2 * p + cg) * 512 + t) * 1024 +
                                      bg * 256 + kg * 64 + ml * 4];
#pragma unroll
    for (int i = 0; i < 16; ++i) {
      const int rg = i * 4 + tq;
      c2[i] = __hip_atomic_load(&hq[(size_t)rg * 256 + 128 + j0], __ATOMIC_RELAXED,
                                __HIP_MEMORY_SCOPE_AGENT);
    }

    // ---- stage chunk 0 (units 0..511) into shared slices ----
#pragma unroll
    for (int i = 0; i < 16; ++i) {
      const int rg = i * 4 + tq, bgr = rg >> 4, row = rg & 15;
      const int un = (j0 >> 1) ^ (row & 7);
      *(u64*)(lds + bgr * 16384 + row * 1024 + un * 16 + (j0 & 1) * 8) = c1[i];
    }
    __syncthreads();
    floatx4 acc[4] = {};
    const char* sl0 = lds + bg * 16384 + ml * 1024;
#pragma unroll
    for (int s = 0; s < 16; ++s) {
      const int un = (s * 4 + kg) ^ (ml & 7);
      half8 a = *(const half8*)(sl0 + un * 16);
      acc[s & 3] = __builtin_amdgcn_mfma_f32_16x16x32_f16(a, wfr[s], acc[s & 3], 0, 0, 0);
    }
    // ---- stage chunk 1 (units 512..1023) ----
#pragma unroll
    for (int i = 0; i < 16; ++i) {
      const int rg = i * 4 + tq, bgr = rg >> 4, row = rg & 15;
      const int un = (j0 >> 1) ^ (row & 7);
      *(u64*)(lds + (4 + bgr) * 16384 + row * 1024 + un * 16 + (j0 & 1) * 8) = c2[i];
    }
    __syncthreads();
    const char* sl1 = lds + (4 + bg) * 16384 + ml * 1024;
#pragma unroll
    for (int s = 0; s < 16; ++s) {
      const int un = (s * 4 + kg) ^ (ml & 7);
      half8 a = *(const half8*)(sl1 + un * 16);
      acc[s & 3] = __builtin_amdgcn_mfma_f32_16x16x32_f16(a, wfr[16 + s], acc[s & 3], 0, 0, 0);
    }
    floatx4 a4 = (acc[0] + acc[1]) + (acc[2] + acc[3]);

    // ---- intra-wave gate exchange in private scratch ----
    union { u64 q; half4v h4; } gu; gu.q = ginb;
#pragma unroll
    for (int r = 0; r < 4; ++r)
      glw[(kg * 4 + r) * 20 + ml] = a4[r] + (float)gu.h4[r];
    __builtin_amdgcn_wave_barrier();
    const float4 g4 = *(const float4*)&glw[bl * 20 + u * 4];

    const float ig = sig_(g4.x), fg = sig_(g4.y);
    const float ag = tanh_(g4.z), og = sig_(g4.w);
    c = fg * c + ig * ag;
    const float h = og * tanh_(c);

    // publish: pack 4 units/batch -> one u64 agent store from lane u==0
    unsigned int mine = (unsigned int)__builtin_bit_cast(unsigned short, (_Float16)h);
    unsigned int pair = mine | (((unsigned int)__shfl_xor((int)mine, 1)) << 16);
    u64 quad = (u64)pair | ((u64)(unsigned int)__shfl_xor((int)pair, 2) << 32);
    if (u == 0)
      __hip_atomic_store(&hnq[(size_t)batch * 256 + 2 * p + cg], quad, __ATOMIC_RELAXED,
                         __HIP_MEMORY_SCOPE_AGENT);

    if (t == 511) {
      out[(size_t)t * 65536 + batch * 1024 + U] = h;
      out[(size_t)33554432 + batch * 1024 + U] = h;  // hy
      out[(size_t)33619968 + batch * 1024 + U] = c;  // cy
      break;
    }

    // ---- grid barrier: contiguous flags, wave0 polls coalesced, LDS token ----
    __builtin_amdgcn_s_waitcnt(0x0F70);  // vmcnt(0): publish acked at coherence point
    __syncthreads();
    const unsigned tgt = (unsigned)(t + 1);
    if (tid == 0)
      __hip_atomic_store(&flags[p], tgt, __ATOMIC_RELAXED, __HIP_MEMORY_SCOPE_AGENT);
    out[(size_t)t * 65536 + batch * 1024 + U] = h;  // off the critical path
    if (w == 0) {
      const u64* f64 = (const u64*)flags;  // 128 flags = 64 u64, one per lane
      int done;
      do {
        u64 v = __hip_atomic_load(&f64[l], __ATOMIC_RELAXED, __HIP_MEMORY_SCOPE_AGENT);
        done = __all(((unsigned)v >= tgt) & ((unsigned)(v >> 32) >= tgt));
      } while (!done);
      __hip_atomic_store(tok, tgt, __ATOMIC_RELAXED, __HIP_MEMORY_SCOPE_WORKGROUP);
    } else {
      while (__hip_atomic_load(tok, __ATOMIC_RELAXED, __HIP_MEMORY_SCOPE_WORKGROUP) < tgt) {}
    }
    asm volatile("" ::: "memory");
  }
}

// ---------------- launch ----------------
extern "C" void kernel_launch(void* const* d_in, const int* in_sizes, int n_in,
                              void* d_out, int out_size, void* d_ws, size_t ws_size,
                              hipStream_t stream) {
  const float* x    = (const float*)d_in[0];
  const float* hx   = (const float*)d_in[1];
  const float* cxp  = (const float*)d_in[2];
  const float* w_ii = (const float*)d_in[3];
  const float* w_fi = (const float*)d_in[4];
  const float* w_ai = (const float*)d_in[5];
  const float* w_oi = (const float*)d_in[6];
  const float* w_ih = (const float*)d_in[7];
  const float* w_fh = (const float*)d_in[8];
  const float* w_ah = (const float*)d_in[9];
  const float* w_oh = (const float*)d_in[10];
  const float* b_i  = (const float*)d_in[11];
  const float* b_f  = (const float*)d_in[12];
  const float* b_a  = (const float*)d_in[13];
  const float* b_o  = (const float*)d_in[14];
  float* out = (float*)d_out;

  char* ws = (char*)d_ws;
  _Float16* Xh        = (_Float16*)(ws);                 // 64 MB (dead after gemm_g)
  unsigned int* flags = (unsigned int*)(ws);             // 512 B used, aliases Xh
  _Float16* Wip       = (_Float16*)(ws + 67108864);      // 8 MB
  _Float16* Whp       = (_Float16*)(ws + 75497472);      // 8 MB
  float* biasp        = (float*)(ws + 83886080);         // 16 KB
  unsigned int* hbuf  = (unsigned int*)(ws + 83902464);  // 256 KB (2 packed buffers)
  _Float16* G3        = (_Float16*)(ws + 84164864);      // 256 MB
  if (ws_size < (size_t)84164864 + 268435456) return;

  cvt_x_kernel<<<32768, 256, 0, stream>>>(x, Xh, 33554432);
  build_w_kernel<<<8193, 256, 0, stream>>>(w_ii, w_fi, w_ai, w_oi, w_ih, w_fh, w_ah, w_oh,
                                           b_i, b_f, b_a, b_o, Wip, Whp, biasp);
  init_h_kernel<<<128, 256, 0, stream>>>(hx, hbuf);
  gemm_g_kernel<<<dim3(256, 32), 256, 0, stream>>>(Xh, Wip, biasp, G3);
  zero_flags_kernel<<<32, 256, 0, stream>>>(flags);
  lstm_rec_kernel<<<128, 512, 0, stream>>>(G3, Whp, hbuf, cxp, out, flags);
}